// Round 7
// baseline (18.706 us; speedup 1.0000x reference)
//
#include <hip/hip_runtime.h>
#include <math.h>

#define EPSF 1e-12f
#define NMAX 2048
#define AT 16            // atoms per block
#define NT 1024          // threads per block
#define SL 64            // j-slices per block (NT/AT)

// ---------------- small float3 helpers ----------------
struct F3 { float x, y, z; };
__device__ __forceinline__ F3 mkf3(float a, float b, float c) { return {a, b, c}; }
__device__ __forceinline__ F3 operator-(F3 a, F3 b) { return {a.x - b.x, a.y - b.y, a.z - b.z}; }
__device__ __forceinline__ F3 operator+(F3 a, F3 b) { return {a.x + b.x, a.y + b.y, a.z + b.z}; }
__device__ __forceinline__ F3 operator-(F3 a) { return {-a.x, -a.y, -a.z}; }
__device__ __forceinline__ F3 operator*(float s, F3 a) { return {s * a.x, s * a.y, s * a.z}; }
__device__ __forceinline__ float dot3(F3 a, F3 b) { return a.x * b.x + a.y * b.y + a.z * b.z; }
__device__ __forceinline__ F3 cross3(F3 a, F3 b) {
    return {a.y * b.z - a.z * b.y, a.z * b.x - a.x * b.z, a.x * b.y - a.y * b.x};
}
__device__ __forceinline__ F3 ldl(const float4* sj, int j) {
    float4 t = sj[j];
    return {t.x, t.y, t.z};
}

// ---------------- bonded contributions (positions from LDS) ----------------
__device__ __forceinline__ F3 bond_force(const float4* sj, int k, int side,
    const float* __restrict__ spring_k, const float* __restrict__ bond_d0,
    const int* __restrict__ bond_tid)
{
    F3 r = ldl(sj, k) - ldl(sj, k + 1);
    float d = sqrtf(dot3(r, r) + EPSF);
    int ty = bond_tid[k];
    float coef = -spring_k[ty] * (d - bond_d0[ty]) / d;
    return (side == 0 ? coef : -coef) * r;
}

__device__ __forceinline__ F3 angle_force(const float4* sj, int k, int p,
    const float* __restrict__ angle_k_arr, const float* __restrict__ angle_th0,
    const int* __restrict__ angle_tid)
{
    F3 p0 = ldl(sj, k), p1 = ldl(sj, k + 1), p2 = ldl(sj, k + 2);
    F3 u = p0 - p1, v = p2 - p1;
    float uu = dot3(u, u), vv = dot3(v, v), uv = dot3(u, v);
    float den = sqrtf(uu * vv + EPSF);
    float c = uv / den;
    const float lo = -1.f + 1e-6f, hi = 1.f - 1e-6f;
    float cl = fminf(fmaxf(c, lo), hi);
    float theta = acosf(cl);
    int ty = angle_tid[k];
    bool inr = (c > lo) && (c < hi);
    float g = inr ? (-angle_k_arr[ty] * (theta - angle_th0[ty]) * rsqrtf(1.f - cl * cl)) : 0.f;
    float invden = 1.f / den;
    float invden3 = invden * invden * invden;
    F3 dcdu = invden * v - (uv * vv * invden3) * u;
    F3 dcdv = invden * u - (uv * uu * invden3) * v;
    F3 F0 = (-g) * dcdu;
    F3 F2 = (-g) * dcdv;
    if (p == 0) return F0;
    if (p == 2) return F2;
    return mkf3(-(F0.x + F2.x), -(F0.y + F2.y), -(F0.z + F2.z));
}

__device__ __forceinline__ F3 dih_force(const float4* sj, int k, int p,
    const float* __restrict__ dih_k_arr, const float* __restrict__ dih_phi0,
    const int* __restrict__ dih_tid)
{
    F3 p0 = ldl(sj, k), p1 = ldl(sj, k + 1), p2 = ldl(sj, k + 2), p3 = ldl(sj, k + 3);
    F3 b1 = p1 - p0, b2 = p2 - p1, b3 = p3 - p2;
    F3 n1 = cross3(b1, b2), n2 = cross3(b2, b3);
    float L2 = dot3(b2, b2) + EPSF;
    float L = sqrtf(L2);
    F3 b2u = (1.f / L) * b2;
    F3 m1 = cross3(n1, b2u);
    float x = dot3(n1, n2), y = dot3(m1, n2);
    float phi = atan2f(y, x);
    int ty = dih_tid[k];
    float dEdphi = dih_k_arr[ty] * (phi - dih_phi0[ty]);
    float inv_xy = 1.f / (x * x + y * y);

    F3 gx_b1 = cross3(b2, n2);
    F3 gx_b2 = cross3(n2, b1) + cross3(b3, n1);
    F3 gx_b3 = cross3(n1, b2);
    F3 bun2 = cross3(b2u, n2);
    F3 gy_b1 = cross3(b2, bun2);
    F3 w = cross3(n2, n1);
    F3 gy_b2 = cross3(bun2, b1) + cross3(b3, m1) + (1.f / L) * (w - (dot3(b2, w) / L2) * b2);
    F3 gy_b3 = cross3(m1, b2);

    float cx = dEdphi * inv_xy;
    F3 dE_b1 = cx * (x * gy_b1 - y * gx_b1);
    F3 dE_b2 = cx * (x * gy_b2 - y * gx_b2);
    F3 dE_b3 = cx * (x * gy_b3 - y * gx_b3);
    if (p == 0) return dE_b1;
    if (p == 1) return dE_b2 - dE_b1;
    if (p == 2) return dE_b3 - dE_b2;
    return -dE_b3;
}

// ---------------- fully fused kernel: one dispatch, no atomics, no ws ----------------
// 512 blocks (2 per CU), 1024 threads, 8 waves/SIMD. Lane-group of 16 lanes
// shares one j-slice; all reads of sj[j] are same-address broadcasts.
__global__ __launch_bounds__(NT, 8) void fused_kernel(
    const float* __restrict__ pos, const float* __restrict__ bead_radii,
    const float* __restrict__ q_vals, const float* __restrict__ spring_k,
    const float* __restrict__ bond_d0, const float* __restrict__ angle_k,
    const float* __restrict__ angle_th0, const float* __restrict__ dih_k,
    const float* __restrict__ dih_phi0, const float* __restrict__ disp_k,
    const float* __restrict__ hbond_k, const float* __restrict__ e_r,
    const float* __restrict__ f_0, const int* __restrict__ bead_types,
    const int* __restrict__ charge_idx, const int* __restrict__ bond_tid,
    const int* __restrict__ angle_tid, const int* __restrict__ dih_tid,
    const int* __restrict__ nb_tid,
    float* __restrict__ out, int N, int n_nbt, int n_bt,
    int nbond, int nang, int ndih)
{
    __shared__ float4 sj[NMAX];        // x,y,z,q of the whole batch
    __shared__ float  srad[NMAX];      // only filled on fallback path
    __shared__ float  red[SL + 8][AT][3];
    __shared__ int    sflag;

    const int tid = threadIdx.x;
    const int b = blockIdx.y;
    const int i0 = blockIdx.x * AT;

    if (tid == 0) sflag = 1;
    __syncthreads();

    const float A0 = disp_k[0], B0 = hbond_k[0], R0 = bead_radii[0];
    for (int t = tid; t < n_nbt; t += NT)
        if (disp_k[t] != A0 || hbond_k[t] != B0) sflag = 0;
    if (tid < n_bt && bead_radii[tid] != R0) sflag = 0;

    // stage whole batch: pos(xyz) + q into float4
    for (int j = tid; j < N; j += NT) {
        const float* pj = pos + ((size_t)b * N + j) * 3;
        sj[j] = make_float4(pj[0], pj[1], pj[2], q_vals[charge_idx[j]]);
    }
    __syncthreads();

    const bool uni = (sflag != 0);
    const int s = tid >> 4;            // slice id, 0..63 (16-lane group)
    const int a = tid & (AT - 1);      // local atom
    const int i = i0 + a;
    const int SLEN = N / SL;           // 32
    const int jbase = s * SLEN;

    const float f0e = f_0[0] / e_r[0];
    const float4 mine = sj[i];
    const float pix = mine.x, piy = mine.y, piz = mine.z;
    const float nqis = -f0e * mine.w;

    float fx = 0.f, fy = 0.f, fz = 0.f;

    if (uni) {
        // constant-folded LJ: lj = u3*fma(K12, u3, K6), u = 1/d2
        const float sig2 = 4.f * R0 * R0;
        const float s2_3 = sig2 * sig2 * sig2;
        const float K6 = 6.f * B0 * s2_3;
        const float K12 = -12.f * A0 * s2_3 * s2_3;
        // wave-uniform: wave covers 4 lane-groups = [wbase, wbase + 4*SLEN)
        const int wbase = (s & ~3) * SLEN;
        const bool needMask = (wbase <= i0 + AT + 1) && (i0 - 2 < wbase + 4 * SLEN);
        if (!needMask) {
#pragma unroll 4
            for (int k = 0; k < SLEN; ++k) {
                float4 pj = sj[jbase + k];
                float rx = pj.x - pix, ry = pj.y - piy, rz = pj.z - piz;
                float d2 = fmaf(rx, rx, fmaf(ry, ry, fmaf(rz, rz, EPSF)));
                float inv = __builtin_amdgcn_rsqf(d2);
                float u = inv * inv;
                float u3 = u * u * u;
                float lj = u3 * fmaf(K12, u3, K6);
                float sc = u * fmaf(nqis * pj.w, inv, lj);
                fx = fmaf(sc, rx, fx); fy = fmaf(sc, ry, fy); fz = fmaf(sc, rz, fz);
            }
        } else {
            const int dj2b = jbase - i + 2;         // (j-i)+2 at k=0
#pragma unroll 4
            for (int k = 0; k < SLEN; ++k) {
                float4 pj = sj[jbase + k];
                float rx = pj.x - pix, ry = pj.y - piy, rz = pj.z - piz;
                float d2 = fmaf(rx, rx, fmaf(ry, ry, fmaf(rz, rz, EPSF)));
                float inv = __builtin_amdgcn_rsqf(d2);
                float u = inv * inv;
                float u3 = u * u * u;
                float lj = u3 * fmaf(K12, u3, K6);
                float sc = u * fmaf(nqis * pj.w, inv, lj);
                bool val = ((unsigned)(dj2b + k)) > 4u;   // |j-i| >= 3
                sc = val ? sc : 0.f;
                fx = fmaf(sc, rx, fx); fy = fmaf(sc, ry, fy); fz = fmaf(sc, rz, fz);
            }
        }
    } else {
        // generic fallback (block-uniform branch): per-pair type lookup
        for (int j = tid; j < N; j += NT)
            srad[j] = bead_radii[bead_types[j]];
        __syncthreads();
        const float radi = srad[i];
        const int basei = i * (N - 3) - (i * (i - 1)) / 2;
        for (int k = 0; k < SLEN; ++k) {
            int j = jbase + k;
            int dj = j - i;
            if (((unsigned)(dj + 2)) > 4u) {
                int pidx = (dj > 0) ? (basei + dj - 3)
                                    : (j * (N - 3) - (j * (j - 1)) / 2 - dj - 3);
                int tt = nb_tid[pidx];
                float A = disp_k[tt], Bc = hbond_k[tt];
                float4 pj = sj[j];
                float rx = pj.x - pix, ry = pj.y - piy, rz = pj.z - piz;
                float d2 = fmaf(rx, rx, fmaf(ry, ry, fmaf(rz, rz, EPSF)));
                float inv = rsqrtf(d2);
                inv = inv * fmaf(-0.5f * d2 * inv, inv, 1.5f);
                float inv2 = inv * inv;
                float sig = radi + srad[j];
                float sr2 = sig * sig * inv2;
                float sr6 = sr2 * sr2 * sr2;
                float lj = sr6 * fmaf(-12.f * A, sr6, 6.f * Bc);
                float sc = inv2 * fmaf(nqis * pj.w, inv, lj);
                fx = fmaf(sc, rx, fx); fy = fmaf(sc, ry, fy); fz = fmaf(sc, rz, fz);
            }
        }
    }
    red[s][a][0] = fx; red[s][a][1] = fy; red[s][a][2] = fz;

    // ---- bonded terms: last 8 lane-groups each take one contribution class.
    //      No live state from the nb loop crosses this branch (results already
    //      parked in red[]), so any register spill stays in this cold path.
    if (s >= SL - 8) {
        const int r = s - (SL - 8);
        F3 F = mkf3(0.f, 0.f, 0.f);
        if (r == 0) {
            if (i <= nbond - 1) F = F + bond_force(sj, i, 0, spring_k, bond_d0, bond_tid);
            if (i >= 1)         F = F + bond_force(sj, i - 1, 1, spring_k, bond_d0, bond_tid);
        } else if (r == 1) {
            if (i <= nang - 1)               F = angle_force(sj, i, 0, angle_k, angle_th0, angle_tid);
        } else if (r == 2) {
            if (i >= 1 && i - 1 <= nang - 1) F = angle_force(sj, i - 1, 1, angle_k, angle_th0, angle_tid);
        } else if (r == 3) {
            if (i >= 2 && i - 2 <= nang - 1) F = angle_force(sj, i - 2, 2, angle_k, angle_th0, angle_tid);
        } else if (r == 4) {
            if (i < ndih)                    F = dih_force(sj, i, 0, dih_k, dih_phi0, dih_tid);
        } else if (r == 5) {
            if (i >= 1 && i - 1 < ndih)      F = dih_force(sj, i - 1, 1, dih_k, dih_phi0, dih_tid);
        } else if (r == 6) {
            if (i >= 2 && i - 2 < ndih)      F = dih_force(sj, i - 2, 2, dih_k, dih_phi0, dih_tid);
        } else {
            if (i >= 3 && i - 3 < ndih)      F = dih_force(sj, i - 3, 3, dih_k, dih_phi0, dih_tid);
        }
        red[SL + r][a][0] = F.x; red[SL + r][a][1] = F.y; red[SL + r][a][2] = F.z;
    }

    __syncthreads();

    // ---- final: AT*3 lanes sum SL+8 partial rows, fully coalesced store
    if (tid < AT * 3) {
        int aa = tid / 3, c = tid - 3 * aa;
        float v = 0.f;
#pragma unroll
        for (int r = 0; r < SL + 8; ++r) v += red[r][aa][c];
        out[((size_t)b * N + i0) * 3 + tid] = v;
    }
}

extern "C" void kernel_launch(void* const* d_in, const int* in_sizes, int n_in,
                              void* d_out, int out_size, void* d_ws, size_t ws_size,
                              hipStream_t stream) {
    const float* pos = (const float*)d_in[0];
    const float* bead_radii = (const float*)d_in[1];
    const float* q_vals = (const float*)d_in[2];
    const float* spring_k = (const float*)d_in[3];
    const float* bond_d0 = (const float*)d_in[4];
    const float* angle_k = (const float*)d_in[5];
    const float* angle_th0 = (const float*)d_in[6];
    const float* dih_k = (const float*)d_in[7];
    const float* dih_phi0 = (const float*)d_in[8];
    const float* disp_k = (const float*)d_in[9];
    const float* hbond_k = (const float*)d_in[10];
    const float* e_r = (const float*)d_in[11];
    const float* f_0 = (const float*)d_in[12];
    const int* bead_types = (const int*)d_in[13];
    const int* charge_idx = (const int*)d_in[14];
    const int* bond_tid = (const int*)d_in[16];
    const int* angle_tid = (const int*)d_in[18];
    const int* dih_tid = (const int*)d_in[20];
    const int* nb_tid = (const int*)d_in[23];
    float* out = (float*)d_out;

    const int N = in_sizes[13];             // 2048
    const int B = in_sizes[0] / (N * 3);    // 4
    const int nbond = in_sizes[16];         // N-1
    const int nang = in_sizes[18];          // N-2
    const int ndih = in_sizes[20];          // 512
    const int n_nbt = in_sizes[9];          // 256
    const int n_bt = in_sizes[1];           // 16

    dim3 grid(N / AT, B);                   // (128, 4) = 512 blocks, 2 per CU
    fused_kernel<<<grid, NT, 0, stream>>>(
        pos, bead_radii, q_vals, spring_k, bond_d0, angle_k, angle_th0,
        dih_k, dih_phi0, disp_k, hbond_k, e_r, f_0,
        bead_types, charge_idx, bond_tid, angle_tid, dih_tid, nb_tid,
        out, N, n_nbt, n_bt, nbond, nang, ndih);
}

// Round 8
// 15.472 us; speedup vs baseline: 1.2090x; 1.2090x over previous
//
#include <hip/hip_runtime.h>
#include <math.h>

#define EPSF 1e-12f
#define NMAX 2048
#define AT 32            // atoms per block
#define NT 1024          // threads per block (16 waves -> 4 waves/SIMD)
#define SL 32            // j-slices per block (NT/AT)

typedef float f2 __attribute__((ext_vector_type(2)));
__device__ __forceinline__ f2 bc2(float x) { f2 r; r.x = x; r.y = x; return r; }

// ---------------- small float3 helpers ----------------
struct F3 { float x, y, z; };
__device__ __forceinline__ F3 mkf3(float a, float b, float c) { return {a, b, c}; }
__device__ __forceinline__ F3 operator-(F3 a, F3 b) { return {a.x - b.x, a.y - b.y, a.z - b.z}; }
__device__ __forceinline__ F3 operator+(F3 a, F3 b) { return {a.x + b.x, a.y + b.y, a.z + b.z}; }
__device__ __forceinline__ F3 operator-(F3 a) { return {-a.x, -a.y, -a.z}; }
__device__ __forceinline__ F3 operator*(float s, F3 a) { return {s * a.x, s * a.y, s * a.z}; }
__device__ __forceinline__ float dot3(F3 a, F3 b) { return a.x * b.x + a.y * b.y + a.z * b.z; }
__device__ __forceinline__ F3 cross3(F3 a, F3 b) {
    return {a.y * b.z - a.z * b.y, a.z * b.x - a.x * b.z, a.x * b.y - a.y * b.x};
}

// ---------------- bonded contributions (positions from LDS SoA) ----------------
__device__ __forceinline__ F3 ldl3(const float* sx, const float* sy, const float* sz, int j) {
    return {sx[j], sy[j], sz[j]};
}

__device__ __forceinline__ F3 bond_force(const float* sx, const float* sy, const float* sz,
    int k, int side,
    const float* __restrict__ spring_k, const float* __restrict__ bond_d0,
    const int* __restrict__ bond_tid)
{
    F3 r = ldl3(sx, sy, sz, k) - ldl3(sx, sy, sz, k + 1);
    float d = sqrtf(dot3(r, r) + EPSF);
    int ty = bond_tid[k];
    float coef = -spring_k[ty] * (d - bond_d0[ty]) / d;
    return (side == 0 ? coef : -coef) * r;
}

__device__ __forceinline__ F3 angle_force(const float* sx, const float* sy, const float* sz,
    int k, int p,
    const float* __restrict__ angle_k_arr, const float* __restrict__ angle_th0,
    const int* __restrict__ angle_tid)
{
    F3 p0 = ldl3(sx, sy, sz, k), p1 = ldl3(sx, sy, sz, k + 1), p2 = ldl3(sx, sy, sz, k + 2);
    F3 u = p0 - p1, v = p2 - p1;
    float uu = dot3(u, u), vv = dot3(v, v), uv = dot3(u, v);
    float den = sqrtf(uu * vv + EPSF);
    float c = uv / den;
    const float lo = -1.f + 1e-6f, hi = 1.f - 1e-6f;
    float cl = fminf(fmaxf(c, lo), hi);
    float theta = acosf(cl);
    int ty = angle_tid[k];
    bool inr = (c > lo) && (c < hi);
    float g = inr ? (-angle_k_arr[ty] * (theta - angle_th0[ty]) * rsqrtf(1.f - cl * cl)) : 0.f;
    float invden = 1.f / den;
    float invden3 = invden * invden * invden;
    F3 dcdu = invden * v - (uv * vv * invden3) * u;
    F3 dcdv = invden * u - (uv * uu * invden3) * v;
    F3 F0 = (-g) * dcdu;
    F3 F2 = (-g) * dcdv;
    if (p == 0) return F0;
    if (p == 2) return F2;
    return mkf3(-(F0.x + F2.x), -(F0.y + F2.y), -(F0.z + F2.z));
}

__device__ __forceinline__ F3 dih_force(const float* sx, const float* sy, const float* sz,
    int k, int p,
    const float* __restrict__ dih_k_arr, const float* __restrict__ dih_phi0,
    const int* __restrict__ dih_tid)
{
    F3 p0 = ldl3(sx, sy, sz, k), p1 = ldl3(sx, sy, sz, k + 1);
    F3 p2 = ldl3(sx, sy, sz, k + 2), p3 = ldl3(sx, sy, sz, k + 3);
    F3 b1 = p1 - p0, b2 = p2 - p1, b3 = p3 - p2;
    F3 n1 = cross3(b1, b2), n2 = cross3(b2, b3);
    float L2 = dot3(b2, b2) + EPSF;
    float L = sqrtf(L2);
    F3 b2u = (1.f / L) * b2;
    F3 m1 = cross3(n1, b2u);
    float x = dot3(n1, n2), y = dot3(m1, n2);
    float phi = atan2f(y, x);
    int ty = dih_tid[k];
    float dEdphi = dih_k_arr[ty] * (phi - dih_phi0[ty]);
    float inv_xy = 1.f / (x * x + y * y);

    F3 gx_b1 = cross3(b2, n2);
    F3 gx_b2 = cross3(n2, b1) + cross3(b3, n1);
    F3 gx_b3 = cross3(n1, b2);
    F3 bun2 = cross3(b2u, n2);
    F3 gy_b1 = cross3(b2, bun2);
    F3 w = cross3(n2, n1);
    F3 gy_b2 = cross3(bun2, b1) + cross3(b3, m1) + (1.f / L) * (w - (dot3(b2, w) / L2) * b2);
    F3 gy_b3 = cross3(m1, b2);

    float cx = dEdphi * inv_xy;
    F3 dE_b1 = cx * (x * gy_b1 - y * gx_b1);
    F3 dE_b2 = cx * (x * gy_b2 - y * gx_b2);
    F3 dE_b3 = cx * (x * gy_b3 - y * gx_b3);
    if (p == 0) return dE_b1;
    if (p == 1) return dE_b2 - dE_b1;
    if (p == 2) return dE_b3 - dE_b2;
    return -dE_b3;
}

// ---------------- fully fused kernel: one dispatch, packed dual-f32 nb loop ----------------
__global__ __launch_bounds__(NT) void fused_kernel(
    const float* __restrict__ pos, const float* __restrict__ bead_radii,
    const float* __restrict__ q_vals, const float* __restrict__ spring_k,
    const float* __restrict__ bond_d0, const float* __restrict__ angle_k,
    const float* __restrict__ angle_th0, const float* __restrict__ dih_k,
    const float* __restrict__ dih_phi0, const float* __restrict__ disp_k,
    const float* __restrict__ hbond_k, const float* __restrict__ e_r,
    const float* __restrict__ f_0, const int* __restrict__ bead_types,
    const int* __restrict__ charge_idx, const int* __restrict__ bond_tid,
    const int* __restrict__ angle_tid, const int* __restrict__ dih_tid,
    const int* __restrict__ nb_tid,
    float* __restrict__ out, int N, int n_nbt, int n_bt,
    int nbond, int nang, int ndih)
{
    __shared__ __align__(16) float sx[NMAX];
    __shared__ __align__(16) float sy[NMAX];
    __shared__ __align__(16) float sz[NMAX];
    __shared__ __align__(16) float sq[NMAX];
    __shared__ float  srad[NMAX];      // only filled on fallback path
    __shared__ float  red[SL + 8][AT][3];
    __shared__ int    sflag;

    const int tid = threadIdx.x;
    const int b = blockIdx.y;
    const int i0 = blockIdx.x * AT;

    if (tid == 0) sflag = 1;
    __syncthreads();

    const float A0 = disp_k[0], B0 = hbond_k[0], R0 = bead_radii[0];
    for (int t = tid; t < n_nbt; t += NT)
        if (disp_k[t] != A0 || hbond_k[t] != B0) sflag = 0;
    if (tid < n_bt && bead_radii[tid] != R0) sflag = 0;

    // stage whole batch into SoA
    for (int j = tid; j < N; j += NT) {
        const float* pj = pos + ((size_t)b * N + j) * 3;
        sx[j] = pj[0]; sy[j] = pj[1]; sz[j] = pj[2];
        sq[j] = q_vals[charge_idx[j]];
    }
    __syncthreads();

    const bool uni = (sflag != 0);
    const int s = tid >> 5;            // slice id, 0..31 (32-lane group)
    const int a = tid & (AT - 1);      // local atom
    const int i = i0 + a;
    const int SLEN = N / SL;           // 64
    const int jbase = s * SLEN;

    const float f0e = f_0[0] / e_r[0];
    const float pix = sx[i], piy = sy[i], piz = sz[i];
    const float nqis = -f0e * sq[i];

    float fx = 0.f, fy = 0.f, fz = 0.f;

    if (uni) {
        // constant-folded LJ: lj = u3*fma(K12, u3, K6), u = 1/d2
        const float sig2 = 4.f * R0 * R0;
        const float s2_3 = sig2 * sig2 * sig2;
        const float K6 = 6.f * B0 * s2_3;
        const float K12 = -12.f * A0 * s2_3 * s2_3;
        const f2 K6v = bc2(K6), K12v = bc2(K12);
        const f2 pix2 = bc2(pix), piy2 = bc2(piy), piz2 = bc2(piz);
        const f2 nqis2 = bc2(nqis), eps2 = bc2(EPSF);

        const f2* px2 = reinterpret_cast<const f2*>(sx);
        const f2* py2 = reinterpret_cast<const f2*>(sy);
        const f2* pz2 = reinterpret_cast<const f2*>(sz);
        const f2* pq2 = reinterpret_cast<const f2*>(sq);
        const int kb = jbase >> 1;     // paired index base (jbase even)

        f2 fx2 = bc2(0.f), fy2 = bc2(0.f), fz2 = bc2(0.f);

        // wave-uniform: wave covers 2 lane-groups = [wbase, wbase + 2*SLEN)
        const int wbase = (s & ~1) * SLEN;
        const bool needMask = (wbase <= i0 + AT + 1) && (i0 - 2 < wbase + 2 * SLEN);
        if (!needMask) {
#pragma unroll 4
            for (int k = 0; k < SLEN / 2; ++k) {
                f2 jx = px2[kb + k], jy = py2[kb + k], jz = pz2[kb + k], jq = pq2[kb + k];
                f2 rx = jx - pix2, ry = jy - piy2, rz = jz - piz2;
                f2 d2 = __builtin_elementwise_fma(rx, rx,
                         __builtin_elementwise_fma(ry, ry,
                          __builtin_elementwise_fma(rz, rz, eps2)));
                f2 inv; inv.x = __builtin_amdgcn_rsqf(d2.x); inv.y = __builtin_amdgcn_rsqf(d2.y);
                f2 u = inv * inv;
                f2 u3 = u * u * u;
                f2 lj = u3 * __builtin_elementwise_fma(K12v, u3, K6v);
                f2 cw = nqis2 * jq;
                f2 sc = u * __builtin_elementwise_fma(cw, inv, lj);
                fx2 = __builtin_elementwise_fma(sc, rx, fx2);
                fy2 = __builtin_elementwise_fma(sc, ry, fy2);
                fz2 = __builtin_elementwise_fma(sc, rz, fz2);
            }
        } else {
            const int dj2b = jbase - i + 2;         // (j-i)+2 at j=jbase
#pragma unroll 4
            for (int k = 0; k < SLEN / 2; ++k) {
                f2 jx = px2[kb + k], jy = py2[kb + k], jz = pz2[kb + k], jq = pq2[kb + k];
                f2 rx = jx - pix2, ry = jy - piy2, rz = jz - piz2;
                f2 d2 = __builtin_elementwise_fma(rx, rx,
                         __builtin_elementwise_fma(ry, ry,
                          __builtin_elementwise_fma(rz, rz, eps2)));
                f2 inv; inv.x = __builtin_amdgcn_rsqf(d2.x); inv.y = __builtin_amdgcn_rsqf(d2.y);
                f2 u = inv * inv;
                f2 u3 = u * u * u;
                f2 lj = u3 * __builtin_elementwise_fma(K12v, u3, K6v);
                f2 cw = nqis2 * jq;
                f2 sc = u * __builtin_elementwise_fma(cw, inv, lj);
                int dj0 = dj2b + 2 * k;
                sc.x = ((unsigned)dj0 > 4u) ? sc.x : 0.f;
                sc.y = ((unsigned)(dj0 + 1) > 4u) ? sc.y : 0.f;
                fx2 = __builtin_elementwise_fma(sc, rx, fx2);
                fy2 = __builtin_elementwise_fma(sc, ry, fy2);
                fz2 = __builtin_elementwise_fma(sc, rz, fz2);
            }
        }
        fx = fx2.x + fx2.y; fy = fy2.x + fy2.y; fz = fz2.x + fz2.y;
    } else {
        // generic fallback (block-uniform branch): per-pair type lookup
        for (int j = tid; j < N; j += NT)
            srad[j] = bead_radii[bead_types[j]];
        __syncthreads();
        const float radi = srad[i];
        const int basei = i * (N - 3) - (i * (i - 1)) / 2;
        for (int k = 0; k < SLEN; ++k) {
            int j = jbase + k;
            int dj = j - i;
            if (((unsigned)(dj + 2)) > 4u) {
                int pidx = (dj > 0) ? (basei + dj - 3)
                                    : (j * (N - 3) - (j * (j - 1)) / 2 - dj - 3);
                int tt = nb_tid[pidx];
                float A = disp_k[tt], Bc = hbond_k[tt];
                float rx = sx[j] - pix, ry = sy[j] - piy, rz = sz[j] - piz;
                float d2 = fmaf(rx, rx, fmaf(ry, ry, fmaf(rz, rz, EPSF)));
                float inv = rsqrtf(d2);
                inv = inv * fmaf(-0.5f * d2 * inv, inv, 1.5f);
                float inv2 = inv * inv;
                float sig = radi + srad[j];
                float sr2 = sig * sig * inv2;
                float sr6 = sr2 * sr2 * sr2;
                float lj = sr6 * fmaf(-12.f * A, sr6, 6.f * Bc);
                float sc = inv2 * fmaf(nqis * sq[j], inv, lj);
                fx = fmaf(sc, rx, fx); fy = fmaf(sc, ry, fy); fz = fmaf(sc, rz, fz);
            }
        }
    }
    red[s][a][0] = fx; red[s][a][1] = fy; red[s][a][2] = fz;

    // ---- bonded terms: last 8 lane-groups each take one contribution class
    if (s >= SL - 8) {
        const int r = s - (SL - 8);
        F3 F = mkf3(0.f, 0.f, 0.f);
        if (r == 0) {
            if (i <= nbond - 1) F = F + bond_force(sx, sy, sz, i, 0, spring_k, bond_d0, bond_tid);
            if (i >= 1)         F = F + bond_force(sx, sy, sz, i - 1, 1, spring_k, bond_d0, bond_tid);
        } else if (r == 1) {
            if (i <= nang - 1)               F = angle_force(sx, sy, sz, i, 0, angle_k, angle_th0, angle_tid);
        } else if (r == 2) {
            if (i >= 1 && i - 1 <= nang - 1) F = angle_force(sx, sy, sz, i - 1, 1, angle_k, angle_th0, angle_tid);
        } else if (r == 3) {
            if (i >= 2 && i - 2 <= nang - 1) F = angle_force(sx, sy, sz, i - 2, 2, angle_k, angle_th0, angle_tid);
        } else if (r == 4) {
            if (i < ndih)                    F = dih_force(sx, sy, sz, i, 0, dih_k, dih_phi0, dih_tid);
        } else if (r == 5) {
            if (i >= 1 && i - 1 < ndih)      F = dih_force(sx, sy, sz, i - 1, 1, dih_k, dih_phi0, dih_tid);
        } else if (r == 6) {
            if (i >= 2 && i - 2 < ndih)      F = dih_force(sx, sy, sz, i - 2, 2, dih_k, dih_phi0, dih_tid);
        } else {
            if (i >= 3 && i - 3 < ndih)      F = dih_force(sx, sy, sz, i - 3, 3, dih_k, dih_phi0, dih_tid);
        }
        red[SL + r][a][0] = F.x; red[SL + r][a][1] = F.y; red[SL + r][a][2] = F.z;
    }

    __syncthreads();

    // ---- final: AT*3 lanes sum SL+8 partial rows, fully coalesced store
    if (tid < AT * 3) {
        int aa = tid / 3, c = tid - 3 * aa;
        float v = 0.f;
#pragma unroll
        for (int r = 0; r < SL + 8; ++r) v += red[r][aa][c];
        out[((size_t)b * N + i0) * 3 + tid] = v;
    }
}

extern "C" void kernel_launch(void* const* d_in, const int* in_sizes, int n_in,
                              void* d_out, int out_size, void* d_ws, size_t ws_size,
                              hipStream_t stream) {
    const float* pos = (const float*)d_in[0];
    const float* bead_radii = (const float*)d_in[1];
    const float* q_vals = (const float*)d_in[2];
    const float* spring_k = (const float*)d_in[3];
    const float* bond_d0 = (const float*)d_in[4];
    const float* angle_k = (const float*)d_in[5];
    const float* angle_th0 = (const float*)d_in[6];
    const float* dih_k = (const float*)d_in[7];
    const float* dih_phi0 = (const float*)d_in[8];
    const float* disp_k = (const float*)d_in[9];
    const float* hbond_k = (const float*)d_in[10];
    const float* e_r = (const float*)d_in[11];
    const float* f_0 = (const float*)d_in[12];
    const int* bead_types = (const int*)d_in[13];
    const int* charge_idx = (const int*)d_in[14];
    const int* bond_tid = (const int*)d_in[16];
    const int* angle_tid = (const int*)d_in[18];
    const int* dih_tid = (const int*)d_in[20];
    const int* nb_tid = (const int*)d_in[23];
    float* out = (float*)d_out;

    const int N = in_sizes[13];             // 2048
    const int B = in_sizes[0] / (N * 3);    // 4
    const int nbond = in_sizes[16];         // N-1
    const int nang = in_sizes[18];          // N-2
    const int ndih = in_sizes[20];          // 512
    const int n_nbt = in_sizes[9];          // 256
    const int n_bt = in_sizes[1];           // 16

    dim3 grid(N / AT, B);                   // (64, 4) = 256 blocks, 1 per CU
    fused_kernel<<<grid, NT, 0, stream>>>(
        pos, bead_radii, q_vals, spring_k, bond_d0, angle_k, angle_th0,
        dih_k, dih_phi0, disp_k, hbond_k, e_r, f_0,
        bead_types, charge_idx, bond_tid, angle_tid, dih_tid, nb_tid,
        out, N, n_nbt, n_bt, nbond, nang, ndih);
}